// Round 5
// baseline (1216.177 us; speedup 1.0000x reference)
//
#include <hip/hip_runtime.h>

#define NROWS 32768
#define KCB   8192
#define DDIM  512
#define MT 128
#define KT 128
#define CAP 32
#define MARGIN 4.88e-4f

typedef short bf16x8 __attribute__((ext_vector_type(8)));
typedef float f32x4  __attribute__((ext_vector_type(4)));

// RNE f32 -> bf16 bits
static __device__ __forceinline__ unsigned short f2bf(float f) {
  unsigned u = __float_as_uint(f);
  return (unsigned short)((u + 0x7fffu + ((u >> 16) & 1u)) >> 16);
}

// async global->LDS DMA, 16B per lane; LDS dest = uniform base + lane*16
static __device__ __forceinline__ void gload_lds16(const void* g, void* l) {
  __builtin_amdgcn_global_load_lds(
      (const __attribute__((address_space(1))) unsigned int*)g,
      (__attribute__((address_space(3))) unsigned int*)l, 16, 0, 0);
}

// Exact sequential-FMA dot over d=0..511 (BLAS k-order, bit-matching ref)
static __device__ __forceinline__ float exact_dot(const float* __restrict__ zp,
                                                  const float* __restrict__ ep) {
  float a = 0.f;
#pragma unroll 8
  for (int d = 0; d < DDIM; d += 4) {
    float4 zv = *(const float4*)(zp + d);
    float4 ev = *(const float4*)(ep + d);
    a = fmaf(zv.x, ev.x, a);
    a = fmaf(zv.y, ev.y, a);
    a = fmaf(zv.z, ev.z, a);
    a = fmaf(zv.w, ev.w, a);
  }
  return a;
}

// ---------------------------------------------------------------------------
// Kernel 1: row squared-norms, bit-replicating numpy pairwise summation.
// (validated: absmax 0)
// ---------------------------------------------------------------------------
__global__ __launch_bounds__(256) void sq_pairwise_kernel(
    const float* __restrict__ z, const float* __restrict__ cb,
    float* __restrict__ zsq, float* __restrict__ esq)
{
#pragma clang fp contract(off)
  int gtid = blockIdx.x * 256 + threadIdx.x;
  int row  = gtid >> 5;
  int l    = threadIdx.x & 31;
  if (row >= NROWS + KCB) return;
  const float* src = (row < NROWS) ? (z + (size_t)row * DDIM)
                                   : (cb + (size_t)(row - NROWS) * DDIM);
  int blk = l >> 3, j = l & 7;
  const float* p = src + blk * 128 + j;
  float acc = 0.0f;
#pragma unroll
  for (int t = 0; t < 16; ++t) {
    float v = p[8 * t];
    float q = v * v;
    acc = acc + q;
  }
  float s = acc + __shfl_xor(acc, 1);
  s = s + __shfl_xor(s, 2);
  s = s + __shfl_xor(s, 4);
  float u = s + __shfl_xor(s, 8);
  u = u + __shfl_xor(u, 16);
  if (l == 0) {
    if (row < NROWS) zsq[row] = u;
    else             esq[row - NROWS] = u;
  }
}

// ---------------------------------------------------------------------------
// Kernel cvt: codebook f32 -> bf16 (RNE) into workspace, once.
// ---------------------------------------------------------------------------
__global__ __launch_bounds__(256) void cvt_cb_kernel(
    const float* __restrict__ cb, unsigned short* __restrict__ cbb)
{
  int t = blockIdx.x * 256 + threadIdx.x;
  const float4* src = (const float4*)(cb + (size_t)t * 8);
  float4 f0 = src[0], f1 = src[1];
  ushort4 o0, o1;
  o0.x = f2bf(f0.x); o0.y = f2bf(f0.y); o0.z = f2bf(f0.z); o0.w = f2bf(f0.w);
  o1.x = f2bf(f1.x); o1.y = f2bf(f1.y); o1.z = f2bf(f1.z); o1.w = f2bf(f1.w);
  *(ushort4*)(cbb + (size_t)t * 8) = o0;
  *(ushort4*)(cbb + (size_t)t * 8 + 4) = o1;
}

// ---------------------------------------------------------------------------
// Kernel 2: MFMA bf16 sweep (M=32/wave, DMA staging) -> candidates -> rescore.
// Block: 256 thr = 4 waves; 128 rows/block; wave owns 32 rows (A in regs,
// dual 16x16x32 MFMA per B-fragment). B chunk (128 codes x 64 d) bf16
// double-buffered in LDS via global_load_lds with pre-swizzled source.
// ---------------------------------------------------------------------------
__global__ __launch_bounds__(256, 1) void vq_mfma_kernel(
    const float* __restrict__ z, const float* __restrict__ cb,
    const unsigned short* __restrict__ cbb,
    const float* __restrict__ zsq, const float* __restrict__ esq,
    float* __restrict__ out_zq, float* __restrict__ out_idx,
    double* __restrict__ loss_acc)
{
  __shared__ alignas(16) char BsRaw[2][16384];   // 2 x (128 codes x 64 d x 2B)
  __shared__ int cnt[MT];
  __shared__ int lists[MT][CAP];
  __shared__ unsigned long long bestpk[MT];
  __shared__ double red_sh[4];

  const int tid = threadIdx.x;
  const int l   = tid & 63;
  const int w   = tid >> 6;
  const int row0  = blockIdx.x * MT;
  const int wrow0 = row0 + w * 32;

  for (int i = tid; i < MT; i += 256) { cnt[i] = 0; bestpk[i] = ~0ull; }

  // ---- A fragments: 32 rows x 512 d in registers (bf16), RNE-converted ----
  bf16x8 afragL[16], afragH[16];
  {
    const float* zrowL = z + (size_t)(wrow0 + (l & 15)) * DDIM + ((l >> 4) << 3);
    const float* zrowH = zrowL + 16 * DDIM;
#pragma unroll
    for (int c = 0; c < 16; ++c) {
      float4 f0 = *(const float4*)(zrowL + c * 32);
      float4 f1 = *(const float4*)(zrowL + c * 32 + 4);
      bf16x8 a;
      a[0] = (short)f2bf(f0.x); a[1] = (short)f2bf(f0.y);
      a[2] = (short)f2bf(f0.z); a[3] = (short)f2bf(f0.w);
      a[4] = (short)f2bf(f1.x); a[5] = (short)f2bf(f1.y);
      a[6] = (short)f2bf(f1.z); a[7] = (short)f2bf(f1.w);
      afragL[c] = a;
      f0 = *(const float4*)(zrowH + c * 32);
      f1 = *(const float4*)(zrowH + c * 32 + 4);
      a[0] = (short)f2bf(f0.x); a[1] = (short)f2bf(f0.y);
      a[2] = (short)f2bf(f0.z); a[3] = (short)f2bf(f0.w);
      a[4] = (short)f2bf(f1.x); a[5] = (short)f2bf(f1.y);
      a[6] = (short)f2bf(f1.z); a[7] = (short)f2bf(f1.w);
      afragH[c] = a;
    }
  }

  float zs_r[8];
#pragma unroll
  for (int r = 0; r < 4; ++r) {
    zs_r[r]     = zsq[wrow0 + ((l >> 4) << 2) + r];
    zs_r[4 + r] = zsq[wrow0 + 16 + ((l >> 4) << 2) + r];
  }

  float m_r[8];
#pragma unroll
  for (int r = 0; r < 8; ++r) m_r[r] = 3.4e38f;

  f32x4 accL[8], accH[8];
#pragma unroll
  for (int nf = 0; nf < 8; ++nf) { accL[nf] = (f32x4)0.f; accH[nf] = (f32x4)0.f; }

  // DMA staging: chunk ci -> k0=(ci>>3)*128 codes, d-bytes (ci&7)*128.
  // LDS linear dest; source pre-swizzled so swizzled READ sees logical data.
  const int gswz = (((l & 7) ^ (l >> 3)) << 4);
#define STAGE_DMA(BUF, CI)                                                      \
  {                                                                             \
    int k0s = ((CI) >> 3) * KT;                                                 \
    int d0b = ((CI) & 7) * 128;                                                 \
    const char* gbase = (const char*)cbb + (size_t)k0s * 1024 + d0b + gswz;     \
    _Pragma("unroll")                                                           \
    for (int c = 0; c < 4; ++c) {                                               \
      int seg = (w << 2) + c;                                                   \
      gload_lds16(gbase + (size_t)((seg << 3) + (l >> 3)) * 1024,               \
                  &BsRaw[BUF][seg << 10]);                                      \
    }                                                                           \
  }

  __syncthreads();
  STAGE_DMA(0, 0)

  const int rbase = (l & 15) * 128;
  const int dsw   = ((l >> 4) << 4);
  const int lxor  = (l & 7) << 4;

  for (int ci = 0; ci < 512; ++ci) {
    __syncthreads();   // drains DMA(ci) [vmcnt(0)] + prior buf reads [lgkm]
    if (ci + 1 < 512) STAGE_DMA((ci + 1) & 1, ci + 1)
    const char* bufp = &BsRaw[ci & 1][0];
    const int ai = (ci & 7) << 1;
#pragma unroll
    for (int nf = 0; nf < 8; ++nf) {
#pragma unroll
      for (int sub = 0; sub < 2; ++sub) {
        int off = nf * 2048 + rbase + ((sub * 64 + dsw) ^ lxor);
        bf16x8 bfrag = *(const bf16x8*)(bufp + off);
        accL[nf] = __builtin_amdgcn_mfma_f32_16x16x32_bf16(afragL[ai + sub], bfrag,
                                                           accL[nf], 0, 0, 0);
        accH[nf] = __builtin_amdgcn_mfma_f32_16x16x32_bf16(afragH[ai + sub], bfrag,
                                                           accH[nf], 0, 0, 0);
      }
    }

    if ((ci & 7) == 7) {
      // ---- per-k-tile epilogue: approx dist, running min, candidate push ----
      int k0 = (ci >> 3) * KT;
      float eq[8];
#pragma unroll
      for (int nf = 0; nf < 8; ++nf) eq[nf] = esq[k0 + (nf << 4) + (l & 15)];
#pragma unroll
      for (int nf = 0; nf < 8; ++nf)
#pragma unroll
        for (int r = 0; r < 4; ++r) {
          accL[nf][r] = (zs_r[r] + eq[nf]) - 2.0f * accL[nf][r];
          accH[nf][r] = (zs_r[4 + r] + eq[nf]) - 2.0f * accH[nf][r];
        }
#pragma unroll
      for (int r = 0; r < 4; ++r) {
        float vL = fminf(fminf(fminf(accL[0][r], accL[1][r]), fminf(accL[2][r], accL[3][r])),
                         fminf(fminf(accL[4][r], accL[5][r]), fminf(accL[6][r], accL[7][r])));
        float vH = fminf(fminf(fminf(accH[0][r], accH[1][r]), fminf(accH[2][r], accH[3][r])),
                         fminf(fminf(accH[4][r], accH[5][r]), fminf(accH[6][r], accH[7][r])));
        vL = fminf(vL, __shfl_xor(vL, 1));
        vL = fminf(vL, __shfl_xor(vL, 2));
        vL = fminf(vL, __shfl_xor(vL, 4));
        vL = fminf(vL, __shfl_xor(vL, 8));
        vH = fminf(vH, __shfl_xor(vH, 1));
        vH = fminf(vH, __shfl_xor(vH, 2));
        vH = fminf(vH, __shfl_xor(vH, 4));
        vH = fminf(vH, __shfl_xor(vH, 8));
        m_r[r]     = fminf(m_r[r], vL);
        m_r[4 + r] = fminf(m_r[4 + r], vH);
      }
      bool anyq = false;
#pragma unroll
      for (int nf = 0; nf < 8; ++nf)
#pragma unroll
        for (int r = 0; r < 4; ++r) {
          anyq |= (accL[nf][r] <= m_r[r] + MARGIN);
          anyq |= (accH[nf][r] <= m_r[4 + r] + MARGIN);
        }
      if (__any(anyq)) {
        int rowbase = (w << 5) + ((l >> 4) << 2);
#pragma unroll
        for (int nf = 0; nf < 8; ++nf)
#pragma unroll
          for (int r = 0; r < 4; ++r) {
            if (accL[nf][r] <= m_r[r] + MARGIN) {
              int pos = atomicAdd(&cnt[rowbase + r], 1);
              if (pos < CAP) lists[rowbase + r][pos] = k0 + (nf << 4) + (l & 15);
            }
            if (accH[nf][r] <= m_r[4 + r] + MARGIN) {
              int pos = atomicAdd(&cnt[rowbase + 16 + r], 1);
              if (pos < CAP) lists[rowbase + 16 + r][pos] = k0 + (nf << 4) + (l & 15);
            }
          }
      }
#pragma unroll
      for (int nf = 0; nf < 8; ++nf) { accL[nf] = (f32x4)0.f; accH[nf] = (f32x4)0.f; }
    }
  }
  __syncthreads();

  // ---- exact rescore of candidates (bit-matching ref numerics) ----
  {
    int r = tid >> 1;
    int grow = row0 + r;
    int c = cnt[r] < CAP ? cnt[r] : CAP;
    const float* zp = z + (size_t)grow * DDIM;
    float zsv = zsq[grow];
    for (int s = tid & 1; s < c; s += 2) {
      int k = lists[r][s];
      float dot = exact_dot(zp, cb + (size_t)k * DDIM);
      float dist = (zsv + esq[k]) - 2.0f * dot;
      unsigned long long pk =
          ((unsigned long long)__float_as_uint(dist) << 32) | (unsigned)k;
      atomicMin(&bestpk[r], pk);
    }
  }
  __syncthreads();

  // ---- overflow fallback: full exact scan for any row with cnt > CAP ----
  for (int r2 = 0; r2 < MT; ++r2) {
    if (cnt[r2] > CAP) {
      int grow = row0 + r2;
      const float* zp = z + (size_t)grow * DDIM;
      float zsv = zsq[grow];
      for (int k = tid; k < KCB; k += 256) {
        float dot = exact_dot(zp, cb + (size_t)k * DDIM);
        float dist = (zsv + esq[k]) - 2.0f * dot;
        unsigned long long pk =
            ((unsigned long long)__float_as_uint(dist) << 32) | (unsigned)k;
        atomicMin(&bestpk[r2], pk);
      }
    }
  }
  __syncthreads();

  // ---- output epilogue: indices, z_q_st, loss (validated) ----
  if (tid < MT) out_idx[row0 + tid] = (float)(unsigned)(bestpk[tid] & 0xffffffffu);

  double lsum = 0.0;
  for (int t4 = tid; t4 < MT * (DDIM / 4); t4 += 256) {
    int r   = t4 >> 7;
    int c4  = t4 & 127;
    int grow = row0 + r;
    int kidx = (int)(unsigned)(bestpk[r] & 0xffffffffu);
    float4 zv  = *(const float4*)(z  + (size_t)grow * DDIM + (c4 << 2));
    float4 cv4 = *(const float4*)(cb + (size_t)kidx * DDIM + (c4 << 2));
    float t0 = cv4.x - zv.x;
    float t1 = cv4.y - zv.y;
    float t2 = cv4.z - zv.z;
    float t3 = cv4.w - zv.w;
    float4 o;
    o.x = zv.x + t0; o.y = zv.y + t1; o.z = zv.z + t2; o.w = zv.w + t3;
    *(float4*)(out_zq + (size_t)grow * DDIM + (c4 << 2)) = o;
    lsum += (double)t0 * t0 + (double)t1 * t1 + (double)t2 * t2 + (double)t3 * t3;
  }
#pragma unroll
  for (int off = 32; off >= 1; off >>= 1) lsum += __shfl_xor(lsum, off);
  if ((tid & 63) == 0) red_sh[tid >> 6] = lsum;
  __syncthreads();
  if (tid == 0) {
    double s = (red_sh[0] + red_sh[1]) + (red_sh[2] + red_sh[3]);
    atomicAdd(loss_acc, s);
  }
}

// ---------------------------------------------------------------------------
// FALLBACK (validated round 2): fp32 VALU fused GEMM+argmin, if ws too small.
// ---------------------------------------------------------------------------
#define FMT 64
#define FDC 32
__global__ __launch_bounds__(256) void vq_main_kernel(
    const float* __restrict__ z, const float* __restrict__ cb,
    const float* __restrict__ zsq, const float* __restrict__ esq,
    float* __restrict__ out_zq, float* __restrict__ out_idx,
    double* __restrict__ loss_acc)
{
  __shared__ float As[FDC][68];
  __shared__ float Bs[FDC][140];
  __shared__ int   idx_sh[FMT];
  __shared__ double red_sh[4];

  const int tid  = threadIdx.x;
  const int row0 = blockIdx.x * FMT;
  const int ty = tid >> 4;
  const int tx = tid & 15;

  const int arow = tid >> 2;
  const int adof = (tid & 3) << 3;
  const int brow = tid >> 1;
  const int bdof = (tid & 1) << 4;
  const int bcolw = brow + ((brow >> 5) << 2);
  const int bcolr = (tx << 3) + ((tx >> 2) << 2);

  float zs[4];
#pragma unroll
  for (int i = 0; i < 4; ++i) zs[i] = zsq[row0 + (ty << 2) + i];

  float bvbest[4]; int bibest[4];
#pragma unroll
  for (int i = 0; i < 4; ++i) { bvbest[i] = 3.402823466e38f; bibest[i] = 0x7fffffff; }

  for (int k0 = 0; k0 < KCB; k0 += KT) {
    float acc[4][8];
#pragma unroll
    for (int i = 0; i < 4; ++i)
#pragma unroll
      for (int jj = 0; jj < 8; ++jj) acc[i][jj] = 0.0f;

    for (int d0 = 0; d0 < DDIM; d0 += FDC) {
      const float4* ag = (const float4*)(z + (size_t)(row0 + arow) * DDIM + d0 + adof);
      float4 a0 = ag[0];
      float4 a1 = ag[1];
      const float4* bg = (const float4*)(cb + (size_t)(k0 + brow) * DDIM + d0 + bdof);
      float4 b0 = bg[0], b1 = bg[1], b2 = bg[2], b3 = bg[3];
      __syncthreads();
      As[adof + 0][arow] = a0.x; As[adof + 1][arow] = a0.y;
      As[adof + 2][arow] = a0.z; As[adof + 3][arow] = a0.w;
      As[adof + 4][arow] = a1.x; As[adof + 5][arow] = a1.y;
      As[adof + 6][arow] = a1.z; As[adof + 7][arow] = a1.w;
      Bs[bdof +  0][bcolw] = b0.x; Bs[bdof +  1][bcolw] = b0.y;
      Bs[bdof +  2][bcolw] = b0.z; Bs[bdof +  3][bcolw] = b0.w;
      Bs[bdof +  4][bcolw] = b1.x; Bs[bdof +  5][bcolw] = b1.y;
      Bs[bdof +  6][bcolw] = b1.z; Bs[bdof +  7][bcolw] = b1.w;
      Bs[bdof +  8][bcolw] = b2.x; Bs[bdof +  9][bcolw] = b2.y;
      Bs[bdof + 10][bcolw] = b2.z; Bs[bdof + 11][bcolw] = b2.w;
      Bs[bdof + 12][bcolw] = b3.x; Bs[bdof + 13][bcolw] = b3.y;
      Bs[bdof + 14][bcolw] = b3.z; Bs[bdof + 15][bcolw] = b3.w;
      __syncthreads();
#pragma unroll 8
      for (int dc = 0; dc < FDC; ++dc) {
        float4 a4 = *(const float4*)&As[dc][ty << 2];
        float4 p0 = *(const float4*)&Bs[dc][bcolr];
        float4 p1 = *(const float4*)&Bs[dc][bcolr + 4];
        float av[4] = {a4.x, a4.y, a4.z, a4.w};
        float bw[8] = {p0.x, p0.y, p0.z, p0.w, p1.x, p1.y, p1.z, p1.w};
#pragma unroll
        for (int i = 0; i < 4; ++i)
#pragma unroll
          for (int jj = 0; jj < 8; ++jj)
            acc[i][jj] += av[i] * bw[jj];
      }
    }

    float ek[8];
#pragma unroll
    for (int jj = 0; jj < 8; ++jj) ek[jj] = esq[k0 + (tx << 3) + jj];
#pragma unroll
    for (int i = 0; i < 4; ++i) {
      float cv = 3.402823466e38f; int ci = 0x7fffffff;
#pragma unroll
      for (int jj = 0; jj < 8; ++jj) {
        int k = k0 + (tx << 3) + jj;
        float t1 = zs[i] + ek[jj];
        float dist = t1 - 2.0f * acc[i][jj];
        if (dist < cv || (dist == cv && k < ci)) { cv = dist; ci = k; }
      }
#pragma unroll
      for (int off = 1; off < 16; off <<= 1) {
        float ov = __shfl_xor(cv, off);
        int   oi = __shfl_xor(ci, off);
        if (ov < cv || (ov == cv && oi < ci)) { cv = ov; ci = oi; }
      }
      if (cv < bvbest[i] || (cv == bvbest[i] && ci < bibest[i])) {
        bvbest[i] = cv; bibest[i] = ci;
      }
    }
  }

  if (tx == 0) {
#pragma unroll
    for (int i = 0; i < 4; ++i) idx_sh[(ty << 2) + i] = bibest[i];
  }
  __syncthreads();

  double lsum = 0.0;
  for (int t4 = tid; t4 < FMT * (DDIM / 4); t4 += 256) {
    int r   = t4 >> 7;
    int c4  = t4 & 127;
    int grow = row0 + r;
    int kidx = idx_sh[r];
    float4 zv  = *(const float4*)(z  + (size_t)grow * DDIM + (c4 << 2));
    float4 cv4 = *(const float4*)(cb + (size_t)kidx * DDIM + (c4 << 2));
    float t0 = cv4.x - zv.x;
    float t1 = cv4.y - zv.y;
    float t2 = cv4.z - zv.z;
    float t3 = cv4.w - zv.w;
    float4 o;
    o.x = zv.x + t0; o.y = zv.y + t1; o.z = zv.z + t2; o.w = zv.w + t3;
    *(float4*)(out_zq + (size_t)grow * DDIM + (c4 << 2)) = o;
    lsum += (double)t0 * t0 + (double)t1 * t1 + (double)t2 * t2 + (double)t3 * t3;
  }
#pragma unroll
  for (int off = 32; off >= 1; off >>= 1) lsum += __shfl_xor(lsum, off);
  if ((tid & 63) == 0) red_sh[tid >> 6] = lsum;
  __syncthreads();
  if (tid == 0) {
    double s = (red_sh[0] + red_sh[1]) + (red_sh[2] + red_sh[3]);
    atomicAdd(loss_acc, s);
  }

  if (tid < FMT) out_idx[row0 + tid] = (float)idx_sh[tid];
}

// ---------------------------------------------------------------------------
// Kernel 3: finalize scalar losses.
// ---------------------------------------------------------------------------
__global__ void vq_finalize_kernel(const double* __restrict__ loss_acc,
                                   float* __restrict__ out_sc)
{
  double m = loss_acc[0] * (1.0 / 16777216.0);
  float mf = (float)m;
  out_sc[0] = mf;
  out_sc[1] = 0.25f * mf;
}

extern "C" void kernel_launch(void* const* d_in, const int* in_sizes, int n_in,
                              void* d_out, int out_size, void* d_ws, size_t ws_size,
                              hipStream_t stream)
{
  const float* z  = (const float*)d_in[0];
  const float* cb = (const float*)d_in[1];
  float* out     = (float*)d_out;
  float* out_zq  = out;
  float* out_idx = out + (size_t)NROWS * DDIM;
  float* out_sc  = out_idx + NROWS;

  double* acc = (double*)d_ws;
  float* zsq = (float*)((char*)d_ws + 256);
  float* esq = zsq + NROWS;
  unsigned short* cbb = (unsigned short*)((char*)d_ws + (1 << 20));

  hipMemsetAsync(d_ws, 0, 8, stream);
  hipLaunchKernelGGL(sq_pairwise_kernel, dim3((NROWS + KCB) / 8), dim3(256), 0, stream,
                     z, cb, zsq, esq);
  if (ws_size >= (size_t)10 * 1024 * 1024) {
    hipLaunchKernelGGL(cvt_cb_kernel, dim3(KCB * DDIM / 8 / 256), dim3(256), 0, stream,
                       cb, cbb);
    hipLaunchKernelGGL(vq_mfma_kernel, dim3(NROWS / MT), dim3(256), 0, stream,
                       z, cb, cbb, zsq, esq, out_zq, out_idx, acc);
  } else {
    hipLaunchKernelGGL(vq_main_kernel, dim3(NROWS / 64), dim3(256), 0, stream,
                       z, cb, zsq, esq, out_zq, out_idx, acc);
  }
  hipLaunchKernelGGL(vq_finalize_kernel, dim3(1), dim3(1), 0, stream, acc, out_sc);
}

// Round 6
// 1002.935 us; speedup vs baseline: 1.2126x; 1.2126x over previous
//
#include <hip/hip_runtime.h>

#define NROWS 32768
#define KCB   8192
#define DDIM  512
#define MT 128
#define KT 128
#define CAP 32
#define MARGIN 4.88e-4f

typedef short bf16x8 __attribute__((ext_vector_type(8)));
typedef float f32x4  __attribute__((ext_vector_type(4)));

// RNE f32 -> bf16 bits
static __device__ __forceinline__ unsigned short f2bf(float f) {
  unsigned u = __float_as_uint(f);
  return (unsigned short)((u + 0x7fffu + ((u >> 16) & 1u)) >> 16);
}

// async global->LDS DMA, 16B per lane; LDS dest = uniform base + lane*16
static __device__ __forceinline__ void gload_lds16(const void* g, void* l) {
  __builtin_amdgcn_global_load_lds(
      (const __attribute__((address_space(1))) unsigned int*)g,
      (__attribute__((address_space(3))) unsigned int*)l, 16, 0, 0);
}

// Exact sequential-FMA dot over d=0..511 (BLAS k-order, bit-matching ref)
static __device__ __forceinline__ float exact_dot(const float* __restrict__ zp,
                                                  const float* __restrict__ ep) {
  float a = 0.f;
#pragma unroll 8
  for (int d = 0; d < DDIM; d += 4) {
    float4 zv = *(const float4*)(zp + d);
    float4 ev = *(const float4*)(ep + d);
    a = fmaf(zv.x, ev.x, a);
    a = fmaf(zv.y, ev.y, a);
    a = fmaf(zv.z, ev.z, a);
    a = fmaf(zv.w, ev.w, a);
  }
  return a;
}

// ---------------------------------------------------------------------------
// Kernel 1: row squared-norms, bit-replicating numpy pairwise summation.
// (validated: absmax 0)
// ---------------------------------------------------------------------------
__global__ __launch_bounds__(256) void sq_pairwise_kernel(
    const float* __restrict__ z, const float* __restrict__ cb,
    float* __restrict__ zsq, float* __restrict__ esq)
{
#pragma clang fp contract(off)
  int gtid = blockIdx.x * 256 + threadIdx.x;
  int row  = gtid >> 5;
  int l    = threadIdx.x & 31;
  if (row >= NROWS + KCB) return;
  const float* src = (row < NROWS) ? (z + (size_t)row * DDIM)
                                   : (cb + (size_t)(row - NROWS) * DDIM);
  int blk = l >> 3, j = l & 7;
  const float* p = src + blk * 128 + j;
  float acc = 0.0f;
#pragma unroll
  for (int t = 0; t < 16; ++t) {
    float v = p[8 * t];
    float q = v * v;
    acc = acc + q;
  }
  float s = acc + __shfl_xor(acc, 1);
  s = s + __shfl_xor(s, 2);
  s = s + __shfl_xor(s, 4);
  float u = s + __shfl_xor(s, 8);
  u = u + __shfl_xor(u, 16);
  if (l == 0) {
    if (row < NROWS) zsq[row] = u;
    else             esq[row - NROWS] = u;
  }
}

// ---------------------------------------------------------------------------
// Kernel cvt: codebook f32 -> bf16 (RNE) into workspace, once.
// ---------------------------------------------------------------------------
__global__ __launch_bounds__(256) void cvt_cb_kernel(
    const float* __restrict__ cb, unsigned short* __restrict__ cbb)
{
  int t = blockIdx.x * 256 + threadIdx.x;
  const float4* src = (const float4*)(cb + (size_t)t * 8);
  float4 f0 = src[0], f1 = src[1];
  ushort4 o0, o1;
  o0.x = f2bf(f0.x); o0.y = f2bf(f0.y); o0.z = f2bf(f0.z); o0.w = f2bf(f0.w);
  o1.x = f2bf(f1.x); o1.y = f2bf(f1.y); o1.z = f2bf(f1.z); o1.w = f2bf(f1.w);
  *(ushort4*)(cbb + (size_t)t * 8) = o0;
  *(ushort4*)(cbb + (size_t)t * 8 + 4) = o1;
}

// ---------------------------------------------------------------------------
// Kernel 2: MFMA bf16 sweep, 4-buffer counted-vmcnt DMA pipeline (T3/T4),
// static A-fragment indexing, esq staged in LDS.
// Block: 256 thr = 4 waves; 128 rows/block; wave owns 32 rows.
// ---------------------------------------------------------------------------
__global__ __launch_bounds__(256, 1) void vq_mfma_kernel(
    const float* __restrict__ z, const float* __restrict__ cb,
    const unsigned short* __restrict__ cbb,
    const float* __restrict__ zsq, const float* __restrict__ esq,
    float* __restrict__ out_zq, float* __restrict__ out_idx,
    double* __restrict__ loss_acc)
{
  __shared__ alignas(16) char BsRaw[4][16384];   // 4 x (128 codes x 64 d x 2B)
  __shared__ float esq_lds[KCB];                 // 32 KB
  __shared__ int cnt[MT];
  __shared__ int lists[MT][CAP];
  __shared__ unsigned long long bestpk[MT];
  __shared__ double red_sh[4];

  const int tid = threadIdx.x;
  const int l   = tid & 63;
  const int w   = tid >> 6;
  const int row0  = blockIdx.x * MT;
  const int wrow0 = row0 + w * 32;

  for (int i = tid; i < MT; i += 256) { cnt[i] = 0; bestpk[i] = ~0ull; }

  // ---- esq -> LDS (32 KB) ----
  for (int i = tid; i < KCB / 4; i += 256) {
    float4 v = *(const float4*)(esq + i * 4);
    *(float4*)&esq_lds[i * 4] = v;
  }

  // ---- A fragments: 32 rows x 512 d in registers (bf16), RNE-converted ----
  bf16x8 afragL[16], afragH[16];
  {
    const float* zrowL = z + (size_t)(wrow0 + (l & 15)) * DDIM + ((l >> 4) << 3);
    const float* zrowH = zrowL + 16 * DDIM;
#pragma unroll
    for (int c = 0; c < 16; ++c) {
      float4 f0 = *(const float4*)(zrowL + c * 32);
      float4 f1 = *(const float4*)(zrowL + c * 32 + 4);
      bf16x8 a;
      a[0] = (short)f2bf(f0.x); a[1] = (short)f2bf(f0.y);
      a[2] = (short)f2bf(f0.z); a[3] = (short)f2bf(f0.w);
      a[4] = (short)f2bf(f1.x); a[5] = (short)f2bf(f1.y);
      a[6] = (short)f2bf(f1.z); a[7] = (short)f2bf(f1.w);
      afragL[c] = a;
      f0 = *(const float4*)(zrowH + c * 32);
      f1 = *(const float4*)(zrowH + c * 32 + 4);
      a[0] = (short)f2bf(f0.x); a[1] = (short)f2bf(f0.y);
      a[2] = (short)f2bf(f0.z); a[3] = (short)f2bf(f0.w);
      a[4] = (short)f2bf(f1.x); a[5] = (short)f2bf(f1.y);
      a[6] = (short)f2bf(f1.z); a[7] = (short)f2bf(f1.w);
      afragH[c] = a;
    }
  }

  float zs_r[8];
#pragma unroll
  for (int r = 0; r < 4; ++r) {
    zs_r[r]     = zsq[wrow0 + ((l >> 4) << 2) + r];
    zs_r[4 + r] = zsq[wrow0 + 16 + ((l >> 4) << 2) + r];
  }

  float m_r[8];
#pragma unroll
  for (int r = 0; r < 8; ++r) m_r[r] = 3.4e38f;

  f32x4 accL[8], accH[8];
#pragma unroll
  for (int nf = 0; nf < 8; ++nf) { accL[nf] = (f32x4)0.f; accH[nf] = (f32x4)0.f; }

  // DMA staging: chunk ci -> k0=(ci>>3)*128 codes, d-bytes (ci&7)*128.
  // LDS linear dest; source pre-swizzled so swizzled READ sees logical data.
  const int gswz = (((l & 7) ^ (l >> 3)) << 4);
#define STAGE_DMA(BUF, CI)                                                      \
  {                                                                             \
    int k0s = ((CI) >> 3) * KT;                                                 \
    int d0b = ((CI) & 7) * 128;                                                 \
    const char* gbase = (const char*)cbb + (size_t)k0s * 1024 + d0b + gswz;     \
    _Pragma("unroll")                                                           \
    for (int c = 0; c < 4; ++c) {                                               \
      int seg = (w << 2) + c;                                                   \
      gload_lds16(gbase + (size_t)((seg << 3) + (l >> 3)) * 1024,               \
                  &BsRaw[BUF][seg << 10]);                                      \
    }                                                                           \
  }

  __syncthreads();          // full drain once: esq_lds/A-loads settled
  STAGE_DMA(0, 0)
  STAGE_DMA(1, 1)
  STAGE_DMA(2, 2)

  const int rbase = (l & 15) * 128;
  const int dsw   = ((l >> 4) << 4);
  const int lxor  = (l & 7) << 4;

  for (int kt = 0; kt < 64; ++kt) {
    const int k0 = kt * KT;
#pragma unroll
    for (int dc = 0; dc < 8; ++dc) {
      const int ci = k0 * 4 + dc * 1 + kt * 0 + (kt << 3) - k0 * 4 + 0;  // = kt*8+dc
      const int cichunk = (kt << 3) + dc;
      // wait: allow the 8 loads of chunks ci+1, ci+2 -> chunk ci complete.
      asm volatile("s_waitcnt vmcnt(8) lgkmcnt(0)" ::: "memory");
      __builtin_amdgcn_s_barrier();
      {
        // stage chunk ci+3 (dead re-stage of 511 keeps vmcnt uniform at tail)
        int nx = cichunk + 3;
        int src = nx < 512 ? nx : 511;
        STAGE_DMA((dc + 3) & 3, src)
      }
      const char* bufp = &BsRaw[dc & 3][0];
#pragma unroll
      for (int sub = 0; sub < 2; ++sub) {
#pragma unroll
        for (int nf = 0; nf < 8; ++nf) {
          int off = nf * 2048 + rbase + ((sub * 64 + dsw) ^ lxor);
          bf16x8 bfrag = *(const bf16x8*)(bufp + off);
          accL[nf] = __builtin_amdgcn_mfma_f32_16x16x32_bf16(
              afragL[dc * 2 + sub], bfrag, accL[nf], 0, 0, 0);
          accH[nf] = __builtin_amdgcn_mfma_f32_16x16x32_bf16(
              afragH[dc * 2 + sub], bfrag, accH[nf], 0, 0, 0);
        }
      }
      (void)ci;
    }

    // ---- per-k-tile epilogue: approx dist, running min, candidate push ----
    float eq[8];
#pragma unroll
    for (int nf = 0; nf < 8; ++nf) eq[nf] = esq_lds[k0 + (nf << 4) + (l & 15)];
#pragma unroll
    for (int nf = 0; nf < 8; ++nf)
#pragma unroll
      for (int r = 0; r < 4; ++r) {
        accL[nf][r] = (zs_r[r] + eq[nf]) - 2.0f * accL[nf][r];
        accH[nf][r] = (zs_r[4 + r] + eq[nf]) - 2.0f * accH[nf][r];
      }
#pragma unroll
    for (int r = 0; r < 4; ++r) {
      float vL = fminf(fminf(fminf(accL[0][r], accL[1][r]), fminf(accL[2][r], accL[3][r])),
                       fminf(fminf(accL[4][r], accL[5][r]), fminf(accL[6][r], accL[7][r])));
      float vH = fminf(fminf(fminf(accH[0][r], accH[1][r]), fminf(accH[2][r], accH[3][r])),
                       fminf(fminf(accH[4][r], accH[5][r]), fminf(accH[6][r], accH[7][r])));
      vL = fminf(vL, __shfl_xor(vL, 1));
      vL = fminf(vL, __shfl_xor(vL, 2));
      vL = fminf(vL, __shfl_xor(vL, 4));
      vL = fminf(vL, __shfl_xor(vL, 8));
      vH = fminf(vH, __shfl_xor(vH, 1));
      vH = fminf(vH, __shfl_xor(vH, 2));
      vH = fminf(vH, __shfl_xor(vH, 4));
      vH = fminf(vH, __shfl_xor(vH, 8));
      m_r[r]     = fminf(m_r[r], vL);
      m_r[4 + r] = fminf(m_r[4 + r], vH);
    }
    bool anyq = false;
#pragma unroll
    for (int nf = 0; nf < 8; ++nf)
#pragma unroll
      for (int r = 0; r < 4; ++r) {
        anyq |= (accL[nf][r] <= m_r[r] + MARGIN);
        anyq |= (accH[nf][r] <= m_r[4 + r] + MARGIN);
      }
    if (__any(anyq)) {
      int rowbase = (w << 5) + ((l >> 4) << 2);
#pragma unroll
      for (int nf = 0; nf < 8; ++nf)
#pragma unroll
        for (int r = 0; r < 4; ++r) {
          if (accL[nf][r] <= m_r[r] + MARGIN) {
            int pos = atomicAdd(&cnt[rowbase + r], 1);
            if (pos < CAP) lists[rowbase + r][pos] = k0 + (nf << 4) + (l & 15);
          }
          if (accH[nf][r] <= m_r[4 + r] + MARGIN) {
            int pos = atomicAdd(&cnt[rowbase + 16 + r], 1);
            if (pos < CAP) lists[rowbase + 16 + r][pos] = k0 + (nf << 4) + (l & 15);
          }
        }
    }
#pragma unroll
    for (int nf = 0; nf < 8; ++nf) { accL[nf] = (f32x4)0.f; accH[nf] = (f32x4)0.f; }
  }

  __syncthreads();   // drains dead-buffer DMA + all LDS ops

  // ---- exact rescore of candidates (bit-matching ref numerics) ----
  {
    int r = tid >> 1;
    int grow = row0 + r;
    int c = cnt[r] < CAP ? cnt[r] : CAP;
    const float* zp = z + (size_t)grow * DDIM;
    float zsv = zsq[grow];
    for (int s = tid & 1; s < c; s += 2) {
      int k = lists[r][s];
      float dot = exact_dot(zp, cb + (size_t)k * DDIM);
      float dist = (zsv + esq[k]) - 2.0f * dot;
      unsigned long long pk =
          ((unsigned long long)__float_as_uint(dist) << 32) | (unsigned)k;
      atomicMin(&bestpk[r], pk);
    }
  }
  __syncthreads();

  // ---- overflow fallback: full exact scan for any row with cnt > CAP ----
  for (int r2 = 0; r2 < MT; ++r2) {
    if (cnt[r2] > CAP) {
      int grow = row0 + r2;
      const float* zp = z + (size_t)grow * DDIM;
      float zsv = zsq[grow];
      for (int k = tid; k < KCB; k += 256) {
        float dot = exact_dot(zp, cb + (size_t)k * DDIM);
        float dist = (zsv + esq[k]) - 2.0f * dot;
        unsigned long long pk =
            ((unsigned long long)__float_as_uint(dist) << 32) | (unsigned)k;
        atomicMin(&bestpk[r2], pk);
      }
    }
  }
  __syncthreads();

  // ---- output epilogue: indices, z_q_st, loss (validated) ----
  if (tid < MT) out_idx[row0 + tid] = (float)(unsigned)(bestpk[tid] & 0xffffffffu);

  double lsum = 0.0;
  for (int t4 = tid; t4 < MT * (DDIM / 4); t4 += 256) {
    int r   = t4 >> 7;
    int c4  = t4 & 127;
    int grow = row0 + r;
    int kidx = (int)(unsigned)(bestpk[r] & 0xffffffffu);
    float4 zv  = *(const float4*)(z  + (size_t)grow * DDIM + (c4 << 2));
    float4 cv4 = *(const float4*)(cb + (size_t)kidx * DDIM + (c4 << 2));
    float t0 = cv4.x - zv.x;
    float t1 = cv4.y - zv.y;
    float t2 = cv4.z - zv.z;
    float t3 = cv4.w - zv.w;
    float4 o;
    o.x = zv.x + t0; o.y = zv.y + t1; o.z = zv.z + t2; o.w = zv.w + t3;
    *(float4*)(out_zq + (size_t)grow * DDIM + (c4 << 2)) = o;
    lsum += (double)t0 * t0 + (double)t1 * t1 + (double)t2 * t2 + (double)t3 * t3;
  }
#pragma unroll
  for (int off = 32; off >= 1; off >>= 1) lsum += __shfl_xor(lsum, off);
  if ((tid & 63) == 0) red_sh[tid >> 6] = lsum;
  __syncthreads();
  if (tid == 0) {
    double s = (red_sh[0] + red_sh[1]) + (red_sh[2] + red_sh[3]);
    atomicAdd(loss_acc, s);
  }
}

// ---------------------------------------------------------------------------
// FALLBACK (validated round 2): fp32 VALU fused GEMM+argmin, if ws too small.
// ---------------------------------------------------------------------------
#define FMT 64
#define FDC 32
__global__ __launch_bounds__(256) void vq_main_kernel(
    const float* __restrict__ z, const float* __restrict__ cb,
    const float* __restrict__ zsq, const float* __restrict__ esq,
    float* __restrict__ out_zq, float* __restrict__ out_idx,
    double* __restrict__ loss_acc)
{
  __shared__ float As[FDC][68];
  __shared__ float Bs[FDC][140];
  __shared__ int   idx_sh[FMT];
  __shared__ double red_sh[4];

  const int tid  = threadIdx.x;
  const int row0 = blockIdx.x * FMT;
  const int ty = tid >> 4;
  const int tx = tid & 15;

  const int arow = tid >> 2;
  const int adof = (tid & 3) << 3;
  const int brow = tid >> 1;
  const int bdof = (tid & 1) << 4;
  const int bcolw = brow + ((brow >> 5) << 2);
  const int bcolr = (tx << 3) + ((tx >> 2) << 2);

  float zs[4];
#pragma unroll
  for (int i = 0; i < 4; ++i) zs[i] = zsq[row0 + (ty << 2) + i];

  float bvbest[4]; int bibest[4];
#pragma unroll
  for (int i = 0; i < 4; ++i) { bvbest[i] = 3.402823466e38f; bibest[i] = 0x7fffffff; }

  for (int k0 = 0; k0 < KCB; k0 += KT) {
    float acc[4][8];
#pragma unroll
    for (int i = 0; i < 4; ++i)
#pragma unroll
      for (int jj = 0; jj < 8; ++jj) acc[i][jj] = 0.0f;

    for (int d0 = 0; d0 < DDIM; d0 += FDC) {
      const float4* ag = (const float4*)(z + (size_t)(row0 + arow) * DDIM + d0 + adof);
      float4 a0 = ag[0];
      float4 a1 = ag[1];
      const float4* bg = (const float4*)(cb + (size_t)(k0 + brow) * DDIM + d0 + bdof);
      float4 b0 = bg[0], b1 = bg[1], b2 = bg[2], b3 = bg[3];
      __syncthreads();
      As[adof + 0][arow] = a0.x; As[adof + 1][arow] = a0.y;
      As[adof + 2][arow] = a0.z; As[adof + 3][arow] = a0.w;
      As[adof + 4][arow] = a1.x; As[adof + 5][arow] = a1.y;
      As[adof + 6][arow] = a1.z; As[adof + 7][arow] = a1.w;
      Bs[bdof +  0][bcolw] = b0.x; Bs[bdof +  1][bcolw] = b0.y;
      Bs[bdof +  2][bcolw] = b0.z; Bs[bdof +  3][bcolw] = b0.w;
      Bs[bdof +  4][bcolw] = b1.x; Bs[bdof +  5][bcolw] = b1.y;
      Bs[bdof +  6][bcolw] = b1.z; Bs[bdof +  7][bcolw] = b1.w;
      Bs[bdof +  8][bcolw] = b2.x; Bs[bdof +  9][bcolw] = b2.y;
      Bs[bdof + 10][bcolw] = b2.z; Bs[bdof + 11][bcolw] = b2.w;
      Bs[bdof + 12][bcolw] = b3.x; Bs[bdof + 13][bcolw] = b3.y;
      Bs[bdof + 14][bcolw] = b3.z; Bs[bdof + 15][bcolw] = b3.w;
      __syncthreads();
#pragma unroll 8
      for (int dc = 0; dc < FDC; ++dc) {
        float4 a4 = *(const float4*)&As[dc][ty << 2];
        float4 p0 = *(const float4*)&Bs[dc][bcolr];
        float4 p1 = *(const float4*)&Bs[dc][bcolr + 4];
        float av[4] = {a4.x, a4.y, a4.z, a4.w};
        float bw[8] = {p0.x, p0.y, p0.z, p0.w, p1.x, p1.y, p1.z, p1.w};
#pragma unroll
        for (int i = 0; i < 4; ++i)
#pragma unroll
          for (int jj = 0; jj < 8; ++jj)
            acc[i][jj] += av[i] * bw[jj];
      }
    }

    float ek[8];
#pragma unroll
    for (int jj = 0; jj < 8; ++jj) ek[jj] = esq[k0 + (tx << 3) + jj];
#pragma unroll
    for (int i = 0; i < 4; ++i) {
      float cv = 3.402823466e38f; int ci = 0x7fffffff;
#pragma unroll
      for (int jj = 0; jj < 8; ++jj) {
        int k = k0 + (tx << 3) + jj;
        float t1 = zs[i] + ek[jj];
        float dist = t1 - 2.0f * acc[i][jj];
        if (dist < cv || (dist == cv && k < ci)) { cv = dist; ci = k; }
      }
#pragma unroll
      for (int off = 1; off < 16; off <<= 1) {
        float ov = __shfl_xor(cv, off);
        int   oi = __shfl_xor(ci, off);
        if (ov < cv || (ov == cv && oi < ci)) { cv = ov; ci = oi; }
      }
      if (cv < bvbest[i] || (cv == bvbest[i] && ci < bibest[i])) {
        bvbest[i] = cv; bibest[i] = ci;
      }
    }
  }

  if (tx == 0) {
#pragma unroll
    for (int i = 0; i < 4; ++i) idx_sh[(ty << 2) + i] = bibest[i];
  }
  __syncthreads();

  double lsum = 0.0;
  for (int t4 = tid; t4 < FMT * (DDIM / 4); t4 += 256) {
    int r   = t4 >> 7;
    int c4  = t4 & 127;
    int grow = row0 + r;
    int kidx = idx_sh[r];
    float4 zv  = *(const float4*)(z  + (size_t)grow * DDIM + (c4 << 2));
    float4 cv4 = *(const float4*)(cb + (size_t)kidx * DDIM + (c4 << 2));
    float t0 = cv4.x - zv.x;
    float t1 = cv4.y - zv.y;
    float t2 = cv4.z - zv.z;
    float t3 = cv4.w - zv.w;
    float4 o;
    o.x = zv.x + t0; o.y = zv.y + t1; o.z = zv.z + t2; o.w = zv.w + t3;
    *(float4*)(out_zq + (size_t)grow * DDIM + (c4 << 2)) = o;
    lsum += (double)t0 * t0 + (double)t1 * t1 + (double)t2 * t2 + (double)t3 * t3;
  }
#pragma unroll
  for (int off = 32; off >= 1; off >>= 1) lsum += __shfl_xor(lsum, off);
  if ((tid & 63) == 0) red_sh[tid >> 6] = lsum;
  __syncthreads();
  if (tid == 0) {
    double s = (red_sh[0] + red_sh[1]) + (red_sh[2] + red_sh[3]);
    atomicAdd(loss_acc, s);
  }

  if (tid < FMT) out_idx[row0 + tid] = (float)idx_sh[tid];
}

// ---------------------------------------------------------------------------
// Kernel 3: finalize scalar losses.
// ---------------------------------------------------------------------------
__global__ void vq_finalize_kernel(const double* __restrict__ loss_acc,
                                   float* __restrict__ out_sc)
{
  double m = loss_acc[0] * (1.0 / 16777216.0);
  float mf = (float)m;
  out_sc[0] = mf;
  out_sc[1] = 0.25f * mf;
}

extern "C" void kernel_launch(void* const* d_in, const int* in_sizes, int n_in,
                              void* d_out, int out_size, void* d_ws, size_t ws_size,
                              hipStream_t stream)
{
  const float* z  = (const float*)d_in[0];
  const float* cb = (const float*)d_in[1];
  float* out     = (float*)d_out;
  float* out_zq  = out;
  float* out_idx = out + (size_t)NROWS * DDIM;
  float* out_sc  = out_idx + NROWS;

  double* acc = (double*)d_ws;
  float* zsq = (float*)((char*)d_ws + 256);
  float* esq = zsq + NROWS;
  unsigned short* cbb = (unsigned short*)((char*)d_ws + (1 << 20));

  hipMemsetAsync(d_ws, 0, 8, stream);
  hipLaunchKernelGGL(sq_pairwise_kernel, dim3((NROWS + KCB) / 8), dim3(256), 0, stream,
                     z, cb, zsq, esq);
  if (ws_size >= (size_t)10 * 1024 * 1024) {
    hipLaunchKernelGGL(cvt_cb_kernel, dim3(KCB * DDIM / 8 / 256), dim3(256), 0, stream,
                       cb, cbb);
    hipLaunchKernelGGL(vq_mfma_kernel, dim3(NROWS / MT), dim3(256), 0, stream,
                       z, cb, cbb, zsq, esq, out_zq, out_idx, acc);
  } else {
    hipLaunchKernelGGL(vq_main_kernel, dim3(NROWS / 64), dim3(256), 0, stream,
                       z, cb, zsq, esq, out_zq, out_idx, acc);
  }
  hipLaunchKernelGGL(vq_finalize_kernel, dim3(1), dim3(1), 0, stream, acc, out_sc);
}